// Round 3
// baseline (1116.356 us; speedup 1.0000x reference)
//
#include <hip/hip_runtime.h>
#include <stdint.h>

// ---------------------------------------------------------------------------
// TransformerBlock fused pipeline for MI355X (gfx950), bf16 MFMA path.
//   B=1024, P=9, D=2700, DFF=512.  M = B*P = 9216 rows.
//   N packed = 8192 (q:0..2699, k:2700..5399, v:5400..8099, pad to 8192)
//   K1 padded 2700->2752 (x @ W), K2 = 1024 exactly ([H1|H2] @ [[WC1],[WC2]])
// Round 3: vectorized converters (16B/lane), attn_ln 512 threads + t in LDS,
//          XCD supertile swizzle in gemm_fused.
// ---------------------------------------------------------------------------

#define MROWS  9216
#define NCOLS  8192
#define KP1    2752
#define KP2    1024
#define DMODEL 2700

typedef __bf16 bf16x8 __attribute__((ext_vector_type(8)));
typedef float  f32x4  __attribute__((ext_vector_type(4)));

__device__ __forceinline__ float b2f(unsigned short u) {
  union { unsigned int u; float f; } v; v.u = ((unsigned int)u) << 16; return v.f;
}
__device__ __forceinline__ unsigned short f2b(float f) {
  union { float f; unsigned int u; } v; v.f = f;
  unsigned int r = v.u + 0x7FFFu + ((v.u >> 16) & 1u);   // RNE
  return (unsigned short)(r >> 16);
}

// async global->LDS, 16B per lane (wave-uniform base + lane*16)
__device__ __forceinline__ void gl2lds16(const void* g, void* l) {
  __builtin_amdgcn_global_load_lds(
      (const __attribute__((address_space(1))) void*)g,
      (__attribute__((address_space(3))) void*)l, 16, 0, 0);
}

// ---------------------------------------------------------------------------
// conversion / packing kernels — all 16B/lane stores
// ---------------------------------------------------------------------------

// state fp32 [9216][2700] -> Xb bf16 [9216][2752]; 8 elems/thread
__global__ void cvt_x(const float* __restrict__ src, unsigned short* __restrict__ dst) {
  int idx = blockIdx.x * 256 + threadIdx.x;      // 9216*344 threads
  int r = idx / 344;
  int c0 = (idx - r * 344) * 8;
  uint4 o;
  if (c0 + 8 <= DMODEL) {
    const float4* p = (const float4*)(src + (size_t)r * DMODEL + c0);
    float4 a = p[0], b = p[1];
    o.x = f2b(a.x) | ((unsigned)f2b(a.y) << 16);
    o.y = f2b(a.z) | ((unsigned)f2b(a.w) << 16);
    o.z = f2b(b.x) | ((unsigned)f2b(b.y) << 16);
    o.w = f2b(b.z) | ((unsigned)f2b(b.w) << 16);
  } else {
    unsigned short t[8];
#pragma unroll
    for (int j = 0; j < 8; j++) {
      int c = c0 + j;
      t[j] = (c < DMODEL) ? f2b(src[(size_t)r * DMODEL + c]) : (unsigned short)0;
    }
    o.x = t[0] | ((unsigned)t[1] << 16); o.y = t[2] | ((unsigned)t[3] << 16);
    o.z = t[4] | ((unsigned)t[5] << 16); o.w = t[6] | ((unsigned)t[7] << 16);
  }
  *(uint4*)(dst + (size_t)r * KP1 + c0) = o;
}

// H1,H2 fp32 [9216][512] -> Hb bf16 [9216][1024]; 8 elems/thread
__global__ void cvt_h(const float* __restrict__ H1, const float* __restrict__ H2,
                      unsigned short* __restrict__ dst) {
  int idx = blockIdx.x * 256 + threadIdx.x;      // 9216*128 threads
  int r = idx >> 7;
  int c0 = (idx & 127) * 8;
  const float* srow = (c0 < 512) ? (H1 + (size_t)r * 512 + c0)
                                 : (H2 + (size_t)r * 512 + (c0 - 512));
  const float4* p = (const float4*)srow;
  float4 a = p[0], b = p[1];
  uint4 o;
  o.x = f2b(a.x) | ((unsigned)f2b(a.y) << 16);
  o.y = f2b(a.z) | ((unsigned)f2b(a.w) << 16);
  o.z = f2b(b.x) | ((unsigned)f2b(b.y) << 16);
  o.w = f2b(b.z) | ((unsigned)f2b(b.w) << 16);
  *(uint4*)(dst + (size_t)r * KP2 + c0) = o;
}

// Wq/Wk/Wv fp32 [2700][2700] -> Wt bf16 [8192][2752] (B^T), 64x64 LDS tiles
__global__ void cvt_wqkv(const float* __restrict__ Wq, const float* __restrict__ Wk,
                         const float* __restrict__ Wv, unsigned short* __restrict__ Wt) {
  __shared__ float tile[64][65];
  const int k0 = blockIdx.x * 64, n0 = blockIdx.y * 64;   // grid (43, 128)
  const int tid = threadIdx.x;
#pragma unroll
  for (int i = 0; i < 16; i++) {
    int e = tid + i * 256;
    int kk = e >> 6, nn0 = e & 63;
    int k = k0 + kk, nn = n0 + nn0;
    float v = 0.f;
    if (k < DMODEL && nn < 3 * DMODEL) {
      int sec = (nn >= 5400) ? 2 : ((nn >= 2700) ? 1 : 0);
      int d = nn - sec * DMODEL;
      const float* W = (sec == 0) ? Wq : ((sec == 1) ? Wk : Wv);
      v = W[(size_t)k * DMODEL + d];
    }
    tile[kk][nn0] = v;
  }
  __syncthreads();
  const int kc = (tid & 7) * 8;
#pragma unroll
  for (int i = 0; i < 2; i++) {
    int nn0 = (tid >> 3) + i * 32;
    uint4 o;
    unsigned short t[8];
#pragma unroll
    for (int j = 0; j < 8; j++) t[j] = f2b(tile[kc + j][nn0]);
    o.x = t[0] | ((unsigned)t[1] << 16); o.y = t[2] | ((unsigned)t[3] << 16);
    o.z = t[4] | ((unsigned)t[5] << 16); o.w = t[6] | ((unsigned)t[7] << 16);
    *(uint4*)(Wt + (size_t)(n0 + nn0) * KP1 + k0 + kc) = o;
  }
}

// WC1*/WC2* fp32 [512][2700] -> WCt bf16 [8192][1024], 64x64 LDS tiles
__global__ void cvt_wc(const float* __restrict__ C1q, const float* __restrict__ C1k,
                       const float* __restrict__ C1v, const float* __restrict__ C2q,
                       const float* __restrict__ C2k, const float* __restrict__ C2v,
                       unsigned short* __restrict__ Wt) {
  __shared__ float tile[64][65];
  const int k0 = blockIdx.x * 64, n0 = blockIdx.y * 64;   // grid (16, 128)
  const int tid = threadIdx.x;
#pragma unroll
  for (int i = 0; i < 16; i++) {
    int e = tid + i * 256;
    int kk = e >> 6, nn0 = e & 63;
    int k = k0 + kk, nn = n0 + nn0;
    float v = 0.f;
    if (nn < 3 * DMODEL) {
      int sec = (nn >= 5400) ? 2 : ((nn >= 2700) ? 1 : 0);
      int d = nn - sec * DMODEL;
      const float* W;
      int kr = k;
      if (k < 512) {
        W = (sec == 0) ? C1q : ((sec == 1) ? C1k : C1v);
      } else {
        W = (sec == 0) ? C2q : ((sec == 1) ? C2k : C2v);
        kr = k - 512;
      }
      v = W[(size_t)kr * DMODEL + d];
    }
    tile[kk][nn0] = v;
  }
  __syncthreads();
  const int kc = (tid & 7) * 8;
#pragma unroll
  for (int i = 0; i < 2; i++) {
    int nn0 = (tid >> 3) + i * 32;
    uint4 o;
    unsigned short t[8];
#pragma unroll
    for (int j = 0; j < 8; j++) t[j] = f2b(tile[kc + j][nn0]);
    o.x = t[0] | ((unsigned)t[1] << 16); o.y = t[2] | ((unsigned)t[3] << 16);
    o.z = t[4] | ((unsigned)t[5] << 16); o.w = t[6] | ((unsigned)t[7] << 16);
    *(uint4*)(Wt + (size_t)(n0 + nn0) * KP2 + k0 + kc) = o;
  }
}

// ---------------------------------------------------------------------------
// Fused double GEMM:
//   phase A: mod  = Hb(9216x1024) @ WCt^T(8192x1024)   -> saved packed bf16
//   phase B: main = Xb(9216x2752) @ Wt^T(8192x2752)
//   epilogue: MQ = (main + bmain) * (mod + bmod)  (bf16)
// 128x128 tile, BK=64, 4 waves (2x2) each 64x64 via 4x4 of 16x16x32 MFMA.
// XCD supertile swizzle: 8-wide N bands, M fastest within a band.
// ---------------------------------------------------------------------------
__global__ __launch_bounds__(256, 2) void gemm_fused(
    const unsigned short* __restrict__ Xb,
    const unsigned short* __restrict__ Wt,
    const unsigned short* __restrict__ Hb,
    const unsigned short* __restrict__ WCt,
    unsigned short* __restrict__ MQ,
    const float* __restrict__ bq_, const float* __restrict__ bk_, const float* __restrict__ bv_,
    const float* __restrict__ b1q, const float* __restrict__ b1k, const float* __restrict__ b1v,
    const float* __restrict__ b2q, const float* __restrict__ b2k, const float* __restrict__ b2v)
{
  __shared__ __align__(16) unsigned short As[128 * 64];
  __shared__ __align__(16) unsigned short Bs[128 * 64];
  const int tid = threadIdx.x;
  const int wave = tid >> 6, lane = tid & 63;

  // supertile swizzle: id -> (band of 8 n-tiles) x (72 m-tiles, m fastest)
  const int id = blockIdx.y * 64 + blockIdx.x;       // 0..4607
  const int band = id / 576;
  const int rem = id - band * 576;
  const int mt_ = rem % 72;
  const int ntl = rem / 72;
  const int m0 = mt_ * 128, n0 = (band * 8 + ntl) * 128;

  const int wm = (wave >> 1) * 64, wn = (wave & 1) * 64;
  const int lm = lane & 15, lq = lane >> 4, l7 = lane & 7;

  // staging geometry: phys block p = r*256+tid holds logical row p>>3,
  // k-block (p&7)^(row&7); offsets in ushort elements.
  int prow[4], pcl[4];
  unsigned int ldsoff[4];
#pragma unroll
  for (int r = 0; r < 4; r++) {
    int p = r * 256 + tid;
    prow[r] = p >> 3;
    pcl[r] = ((p & 7) ^ (prow[r] & 7)) * 8;
    ldsoff[r] = (unsigned int)p * 8;
  }

  f32x4 acc[4][4];
#pragma unroll
  for (int i = 0; i < 4; i++)
#pragma unroll
    for (int j = 0; j < 4; j++) acc[i][j] = (f32x4){0.f, 0.f, 0.f, 0.f};

  // ---------------- phase A: modulation GEMM, K = 1024 ----------------
  for (int k0 = 0; k0 < KP2; k0 += 64) {
#pragma unroll
    for (int r = 0; r < 4; r++) {
      gl2lds16(Hb + (size_t)(m0 + prow[r]) * KP2 + pcl[r] + k0, As + ldsoff[r]);
      gl2lds16(WCt + (size_t)(n0 + prow[r]) * KP2 + pcl[r] + k0, Bs + ldsoff[r]);
    }
    __syncthreads();
#pragma unroll
    for (int c = 0; c < 2; c++) {
      bf16x8 af[4], bfr[4];
      const int kx = (c * 4 + lq) ^ l7;
#pragma unroll
      for (int t = 0; t < 4; t++) {
        af[t]  = *(const bf16x8*)(As + (((wm + t * 16 + lm) << 3) + kx) * 8);
        bfr[t] = *(const bf16x8*)(Bs + (((wn + t * 16 + lm) << 3) + kx) * 8);
      }
#pragma unroll
      for (int mt = 0; mt < 4; mt++)
#pragma unroll
        for (int nt = 0; nt < 4; nt++)
          acc[mt][nt] = __builtin_amdgcn_mfma_f32_16x16x32_bf16(
              af[mt], bfr[nt], acc[mt][nt], 0, 0, 0);
    }
    __syncthreads();
  }

  // save modulation (+ bias) packed bf16; reset acc
  unsigned int modp[4][4][2];
#pragma unroll
  for (int nt = 0; nt < 4; nt++) {
    int gc = n0 + wn + nt * 16 + lm;
    float bmod = 0.f;
    if (gc < 3 * DMODEL) {
      int sec = (gc >= 5400) ? 2 : ((gc >= 2700) ? 1 : 0);
      int d = gc - sec * DMODEL;
      const float* u1 = (sec == 0) ? b1q : ((sec == 1) ? b1k : b1v);
      const float* u2 = (sec == 0) ? b2q : ((sec == 1) ? b2k : b2v);
      bmod = u1[d] + u2[d];
    }
#pragma unroll
    for (int mt = 0; mt < 4; mt++) {
#pragma unroll
      for (int h = 0; h < 2; h++) {
        unsigned int lo = f2b(acc[mt][nt][2 * h] + bmod);
        unsigned int hi = f2b(acc[mt][nt][2 * h + 1] + bmod);
        modp[mt][nt][h] = lo | (hi << 16);
      }
    }
  }
#pragma unroll
  for (int i = 0; i < 4; i++)
#pragma unroll
    for (int j = 0; j < 4; j++) acc[i][j] = (f32x4){0.f, 0.f, 0.f, 0.f};

  // ---------------- phase B: main GEMM, K = 2752 ----------------
  for (int k0 = 0; k0 < KP1; k0 += 64) {
#pragma unroll
    for (int r = 0; r < 4; r++) {
      gl2lds16(Xb + (size_t)(m0 + prow[r]) * KP1 + pcl[r] + k0, As + ldsoff[r]);
      gl2lds16(Wt + (size_t)(n0 + prow[r]) * KP1 + pcl[r] + k0, Bs + ldsoff[r]);
    }
    __syncthreads();
#pragma unroll
    for (int c = 0; c < 2; c++) {
      bf16x8 af[4], bfr[4];
      const int kx = (c * 4 + lq) ^ l7;
#pragma unroll
      for (int t = 0; t < 4; t++) {
        af[t]  = *(const bf16x8*)(As + (((wm + t * 16 + lm) << 3) + kx) * 8);
        bfr[t] = *(const bf16x8*)(Bs + (((wn + t * 16 + lm) << 3) + kx) * 8);
      }
#pragma unroll
      for (int mt = 0; mt < 4; mt++)
#pragma unroll
        for (int nt = 0; nt < 4; nt++)
          acc[mt][nt] = __builtin_amdgcn_mfma_f32_16x16x32_bf16(
              af[mt], bfr[nt], acc[mt][nt], 0, 0, 0);
    }
    __syncthreads();
  }

  // ---------------- epilogue: qkv = (main + b) * mod ----------------
#pragma unroll
  for (int nt = 0; nt < 4; nt++) {
    int gc = n0 + wn + nt * 16 + lm;
    float bmv = 0.f;
    if (gc < 3 * DMODEL) {
      int sec = (gc >= 5400) ? 2 : ((gc >= 2700) ? 1 : 0);
      int d = gc - sec * DMODEL;
      const float* bm = (sec == 0) ? bq_ : ((sec == 1) ? bk_ : bv_);
      bmv = bm[d];
    }
#pragma unroll
    for (int mt = 0; mt < 4; mt++) {
      int grb = m0 + wm + mt * 16 + lq * 4;   // C/D: col=lane&15, row=quad*4+i
#pragma unroll
      for (int i = 0; i < 4; i++) {
        float mod = b2f((unsigned short)(modp[mt][nt][i >> 1] >> ((i & 1) * 16)));
        MQ[(size_t)(grb + i) * NCOLS + gc] = f2b((acc[mt][nt][i] + bmv) * mod);
      }
    }
  }
}

// ---------------------------------------------------------------------------
// Fused attention (9x9) + softmax + residual + LayerNorm. One block per batch,
// 512 threads. t-values staged bf16 in LDS (keeps VGPR low -> 2 blocks/CU).
// ---------------------------------------------------------------------------
__global__ __launch_bounds__(512, 4) void attn_ln(
    const unsigned short* __restrict__ qkv,  // [9216][8192] bf16 (q|k|v packed)
    const float* __restrict__ x,             // [9216][2700] fp32
    const float* __restrict__ gamma, const float* __restrict__ beta,
    float* __restrict__ out)                 // [9216][2700] fp32
{
  __shared__ unsigned int tlds[9 * 675 * 2];           // 48.6 KB packed bf16 t
  __shared__ float part[8][81];
  __shared__ float sc[81];
  __shared__ float redS[8][9], redQ[8][9];
  __shared__ float muL[9], rsL[9];

  const int b = blockIdx.x;
  const int tid = threadIdx.x, wave = tid >> 6, lane = tid & 63;
  const unsigned short* qb = qkv + (size_t)b * 9 * NCOLS;

  // ---- phase 1: scores S[i][j] = q_i . k_j via 16x16x32 MFMA, K-split ----
  {
    const int l15 = lane & 15, lq8 = (lane >> 4) * 8;
    const int rA = (l15 < 9) ? l15 : 8;                 // clamp: rows 9..15 junk
    const unsigned short* qrow = qb + (size_t)rA * NCOLS;
    const unsigned short* krow = qb + (size_t)rA * NCOLS + DMODEL;
    f32x4 accS = (f32x4){0.f, 0.f, 0.f, 0.f};
    for (int s = wave; s < 85; s += 8) {                // 85 = ceil(2700/32)
      int k0 = s * 32 + lq8;
      union { uint2 u[2]; unsigned int w[4]; bf16x8 v; } au, bu;
      au.u[0] = *(const uint2*)(qrow + k0);
      au.u[1] = *(const uint2*)(qrow + k0 + 4);
      bu.u[0] = *(const uint2*)(krow + k0);
      bu.u[1] = *(const uint2*)(krow + k0 + 4);
      if (s == 84) {                                    // mask k >= 2700
#pragma unroll
        for (int wd = 0; wd < 4; wd++)
          if (k0 + 2 * wd >= DMODEL) { au.w[wd] = 0u; bu.w[wd] = 0u; }
      }
      accS = __builtin_amdgcn_mfma_f32_16x16x32_bf16(au.v, bu.v, accS, 0, 0, 0);
    }
#pragma unroll
    for (int i = 0; i < 4; i++) {
      int row = (lane >> 4) * 4 + i, col = l15;
      if (row < 9 && col < 9) part[wave][row * 9 + col] = accS[i];
    }
  }
  __syncthreads();

  if (tid < 81) {
    float s = 0.f;
#pragma unroll
    for (int w = 0; w < 8; w++) s += part[w][tid];
    sc[tid] = s * 0.019245008972987526f;                // 1/sqrt(2700)
  }
  __syncthreads();

  // ---- phase 2: softmax per row (threads 0..8) ----
  if (tid < 9) {
    float mx = -1e30f;
#pragma unroll
    for (int j = 0; j < 9; j++) mx = fmaxf(mx, sc[tid * 9 + j]);
    float e[9], sum = 0.f;
#pragma unroll
    for (int j = 0; j < 9; j++) { e[j] = __expf(sc[tid * 9 + j] - mx); sum += e[j]; }
    float inv = 1.f / sum;
#pragma unroll
    for (int j = 0; j < 9; j++) sc[tid * 9 + j] = e[j] * inv;
  }
  __syncthreads();

  // ---- phase 3: t = x + A.V for all 9 rows; stash t bf16 in LDS ----
  float sum[9], sq[9];
#pragma unroll
  for (int i = 0; i < 9; i++) { sum[i] = 0.f; sq[i] = 0.f; }
#pragma unroll
  for (int c = 0; c < 2; c++) {
    int e = tid + c * 512;
    if (e < 675) {                                      // 675 = 2700/4
      float4 t4[9];
#pragma unroll
      for (int i = 0; i < 9; i++)
        t4[i] = ((const float4*)(x + (size_t)(b * 9 + i) * DMODEL))[e];
#pragma unroll
      for (int j = 0; j < 9; j++) {
        ushort4 vv = ((const ushort4*)(qb + (size_t)j * NCOLS + 5400))[e];
        float v0 = b2f(vv.x), v1 = b2f(vv.y), v2 = b2f(vv.z), v3 = b2f(vv.w);
#pragma unroll
        for (int i = 0; i < 9; i++) {
          float p = sc[i * 9 + j];
          t4[i].x += p * v0; t4[i].y += p * v1;
          t4[i].z += p * v2; t4[i].w += p * v3;
        }
      }
#pragma unroll
      for (int i = 0; i < 9; i++) {
        sum[i] += t4[i].x + t4[i].y + t4[i].z + t4[i].w;
        sq[i]  += t4[i].x * t4[i].x + t4[i].y * t4[i].y
                + t4[i].z * t4[i].z + t4[i].w * t4[i].w;
        uint2 pk;
        pk.x = (unsigned int)f2b(t4[i].x) | ((unsigned int)f2b(t4[i].y) << 16);
        pk.y = (unsigned int)f2b(t4[i].z) | ((unsigned int)f2b(t4[i].w) << 16);
        *(uint2*)&tlds[(i * 675 + e) * 2] = pk;
      }
    }
  }

  // ---- phase 4: block reduction for all 9 rows ----
#pragma unroll
  for (int i = 0; i < 9; i++) {
    float s = sum[i], q = sq[i];
#pragma unroll
    for (int off = 32; off > 0; off >>= 1) {
      s += __shfl_down(s, off, 64);
      q += __shfl_down(q, off, 64);
    }
    if (lane == 0) { redS[wave][i] = s; redQ[wave][i] = q; }
  }
  __syncthreads();
  if (tid < 9) {
    float ts = 0.f, tq = 0.f;
#pragma unroll
    for (int w = 0; w < 8; w++) { ts += redS[w][tid]; tq += redQ[w][tid]; }
    float mu = ts * (1.f / 2700.f);
    muL[tid] = mu;
    rsL[tid] = rsqrtf(tq * (1.f / 2700.f) - mu * mu + 1e-5f);
  }
  __syncthreads();

  // ---- phase 5: LN write, float4 ----
#pragma unroll
  for (int c = 0; c < 2; c++) {
    int e = tid + c * 512;
    if (e < 675) {
      float4 g = ((const float4*)gamma)[e];
      float4 bb = ((const float4*)beta)[e];
#pragma unroll
      for (int i = 0; i < 9; i++) {
        float m = muL[i], r = rsL[i];
        uint2 pk = *(const uint2*)&tlds[(i * 675 + e) * 2];
        float t0 = b2f((unsigned short)(pk.x & 0xFFFF));
        float t1 = b2f((unsigned short)(pk.x >> 16));
        float t2 = b2f((unsigned short)(pk.y & 0xFFFF));
        float t3 = b2f((unsigned short)(pk.y >> 16));
        float4 o;
        o.x = (t0 - m) * r * g.x + bb.x;
        o.y = (t1 - m) * r * g.y + bb.y;
        o.z = (t2 - m) * r * g.z + bb.z;
        o.w = (t3 - m) * r * g.w + bb.w;
        ((float4*)(out + (size_t)(b * 9 + i) * DMODEL))[e] = o;
      }
    }
  }
}

// ---------------------------------------------------------------------------
extern "C" void kernel_launch(void* const* d_in, const int* in_sizes, int n_in,
                              void* d_out, int out_size, void* d_ws, size_t ws_size,
                              hipStream_t stream) {
  const float* state = (const float*)d_in[0];
  const float* H1    = (const float*)d_in[1];
  const float* H2    = (const float*)d_in[2];
  const float* Wq    = (const float*)d_in[3];
  const float* bq    = (const float*)d_in[4];
  const float* Wk    = (const float*)d_in[5];
  const float* bk    = (const float*)d_in[6];
  const float* Wv    = (const float*)d_in[7];
  const float* bv    = (const float*)d_in[8];
  const float* WC1q  = (const float*)d_in[9];
  const float* bC1q  = (const float*)d_in[10];
  const float* WC1k  = (const float*)d_in[11];
  const float* bC1k  = (const float*)d_in[12];
  const float* WC1v  = (const float*)d_in[13];
  const float* bC1v  = (const float*)d_in[14];
  const float* WC2q  = (const float*)d_in[15];
  const float* bC2q  = (const float*)d_in[16];
  const float* WC2k  = (const float*)d_in[17];
  const float* bC2k  = (const float*)d_in[18];
  const float* WC2v  = (const float*)d_in[19];
  const float* bC2v  = (const float*)d_in[20];
  const float* gamma = (const float*)d_in[21];
  const float* beta  = (const float*)d_in[22];
  float* out = (float*)d_out;

  // workspace layout (256B aligned), total 282,460,160 B
  char* ws = (char*)d_ws;
  unsigned short* Xb  = (unsigned short*)(ws + 0);            // 9216*2752*2
  unsigned short* Wt  = (unsigned short*)(ws + 50724864);     // 8192*2752*2
  unsigned short* Hb  = (unsigned short*)(ws + 95813632);     // 9216*1024*2
  unsigned short* WCt = (unsigned short*)(ws + 114688000);    // 8192*1024*2
  unsigned short* MQ  = (unsigned short*)(ws + 131465216);    // 9216*8192*2

  // 1) convert / pack (vectorized 16B stores)
  cvt_x<<<dim3(9216 * 344 / 256), dim3(256), 0, stream>>>(state, Xb);
  cvt_wqkv<<<dim3(43, 128), dim3(256), 0, stream>>>(Wq, Wk, Wv, Wt);
  cvt_h<<<dim3(9216 * 128 / 256), dim3(256), 0, stream>>>(H1, H2, Hb);
  cvt_wc<<<dim3(16, 128), dim3(256), 0, stream>>>(WC1q, WC1k, WC1v,
                                                  WC2q, WC2k, WC2v, WCt);

  // 2) fused double GEMM: MQ = (Xb@Wt^T + b) * (Hb@WCt^T + bc)
  gemm_fused<<<dim3(64, 72), dim3(256), 0, stream>>>(
      Xb, Wt, Hb, WCt, MQ, bq, bk, bv, bC1q, bC1k, bC1v, bC2q, bC2k, bC2v);

  // 3) attention + softmax + residual + layernorm (512 threads)
  attn_ln<<<dim3(1024), dim3(512), 0, stream>>>(MQ, state, gamma, beta, out);
}